// Round 19
// baseline (55.268 us; speedup 1.0000x reference)
//
#include <hip/hip_runtime.h>
#include <hip/hip_bf16.h>
#include <math.h>

typedef __attribute__((ext_vector_type(8))) __bf16 bf16x8;
typedef __attribute__((ext_vector_type(4))) float f32x4;

constexpr float VX_ = 0.2f;
constexpr float VY_ = 0.2f;
constexpr float X_OFF_ = 0.1f;    // VX/2 + 0.0
constexpr float Y_OFF_ = -39.9f;  // VY/2 - 40.0
constexpr float EPS_ = 1e-3f;

#define S1 512  // k1 block count; partials = [64][2][S1]

__device__ __forceinline__ float wave_sum(float v) {
#pragma unroll
  for (int off = 32; off; off >>= 1) v += __shfl_xor(v, off);
  return v;
}

__device__ __forceinline__ ushort bf16bits(float x) {
  __hip_bfloat16 h = __float2bfloat16(x);
  return __builtin_bit_cast(ushort, h);
}

// packed RNE f32x2 -> bf16x2 (gfx950 has the instruction but no builtin)
__device__ __forceinline__ uint32_t cvtpk(float lo, float hi) {
  uint32_t r;
  asm("v_cvt_pk_bf16_f32 %0, %1, %2" : "=v"(r) : "v"(lo), "v"(hi));
  return r;
}

// k1: inline concurrent prep (W->LDS, G' = scaled W^T W + wsum) + per-n
// moments pre-contracted to 2 floats/thread + per-pillar aux
// {m0,m1,m2,ox,oy,np}. Non-atomic partials [(n*2+j)*S1 + block].
// Block 0 also packs the MFMA B fragments (B[9][o] = 1.0 bias channel).
__global__ __launch_bounds__(256) void k1_moments(
    const float* __restrict__ feats, const int* __restrict__ npts_arr,
    const int* __restrict__ coors, const float* __restrict__ W,
    float* __restrict__ partials, float* __restrict__ aux,
    uint32_t* __restrict__ Bpack, int P) {
  __shared__ float W_lds[576];
  __shared__ float gws[54];  // G'[45] (off-diag doubled) + wsum[9]
  __shared__ float2 red[4][64];
  const int t = threadIdx.x, lane = t & 63, wv = t >> 6;

  for (int i = t; i < 576; i += 256) W_lds[i] = W[i];
  __syncthreads();
  if (t < 180) {  // G': 45 pairs x 4-way split over o
    const int pr = t >> 2, k = t & 3;
    int c = 0, rem = pr;
    while (rem >= 9 - c) {
      rem -= 9 - c;
      ++c;
    }
    const int c2 = c + rem;
    float s = 0.f;
    for (int o = k * 16; o < k * 16 + 16; ++o)
      s += W_lds[o * 9 + c] * W_lds[o * 9 + c2];
    s += __shfl_xor(s, 1);
    s += __shfl_xor(s, 2);
    if (k == 0) gws[pr] = (c == c2) ? s : 2.f * s;
  } else if (t < 216) {  // wsum: 9 cols x 4-way split
    const int tt = t - 180, c = tt >> 2, k = tt & 3;
    float s = 0.f;
    for (int o = k * 16; o < k * 16 + 16; ++o) s += W_lds[o * 9 + c];
    s += __shfl_xor(s, 1);
    s += __shfl_xor(s, 2);
    if (k == 0) gws[45 + c] = s;
  }
  __syncthreads();
  float g[45], wsv[9];
#pragma unroll
  for (int i = 0; i < 45; ++i) g[i] = gws[i];
#pragma unroll
  for (int i = 0; i < 9; ++i) wsv[i] = gws[45 + i];

  if (blockIdx.x == 0) {  // Bpack build; kk==9 -> 1.0 (bias channel)
    const int nt = t >> 6, bl = t & 63;
    const int l16 = bl & 15, g16 = bl >> 4;
    const int col = nt * 16 + l16;
    ushort h[8];
#pragma unroll
    for (int j = 0; j < 8; ++j) {
      const int kk = 8 * g16 + j;
      h[j] = (kk < 9) ? bf16bits(W_lds[col * 9 + kk])
                      : ((kk == 9) ? bf16bits(1.0f) : (ushort)0);
    }
    uint4 q;
    q.x = (uint)h[0] | ((uint)h[1] << 16);
    q.y = (uint)h[2] | ((uint)h[3] << 16);
    q.z = (uint)h[4] | ((uint)h[5] << 16);
    q.w = (uint)h[6] | ((uint)h[7] << 16);
    *reinterpret_cast<uint4*>(Bpack + (size_t)t * 4) = q;
  }

  float s1 = 0.f, s2 = 0.f;
  const int nw = S1 * 4;
  int p = blockIdx.x * 4 + wv;
  if (p < P) {
    float4 f =
        *reinterpret_cast<const float4*>(feats + (size_t)p * 256 + lane * 4);
    int np = npts_arr[p];
    int cx = coors[p * 4 + 3], cy = coors[p * 4 + 2];
    while (true) {
      const int p2 = p + nw;
      const bool has2 = p2 < P;
      float4 f2 = make_float4(0.f, 0.f, 0.f, 0.f);
      int np2 = 1, cx2 = 0, cy2 = 0;
      if (has2) {  // prefetch next pillar
        f2 = *reinterpret_cast<const float4*>(feats + (size_t)p2 * 256 +
                                              lane * 4);
        np2 = npts_arr[p2];
        cx2 = coors[p2 * 4 + 3];
        cy2 = coors[p2 * 4 + 2];
      }
      const float ox = (float)cx * VX_ + X_OFF_;
      const float oy = (float)cy * VY_ + Y_OFF_;
      const float inv = 1.f / (float)np;
      const float m0 = wave_sum(f.x) * inv;
      const float m1 = wave_sum(f.y) * inv;
      const float m2 = wave_sum(f.z) * inv;
      if (lane == 0) {  // per-pillar aux for k4 (fire-and-forget stores)
        *reinterpret_cast<float4*>(aux + (size_t)p * 8) =
            make_float4(m0, m1, m2, ox);
        *reinterpret_cast<float4*>(aux + (size_t)p * 8 + 4) =
            make_float4(oy, __int_as_float(np), 0.f, 0.f);
      }
      const bool valid = lane < np;
      float ft[9] = {f.x,      f.y,      f.z,      f.w,      f.x - m0,
                     f.y - m1, f.z - m2, f.x - ox, f.y - oy};
#pragma unroll
      for (int c = 0; c < 9; ++c) ft[c] = valid ? ft[c] : 0.f;
      int idx = 0;
      float t1 = 0.f, t2 = 0.f;
#pragma unroll
      for (int c = 0; c < 9; ++c) {
        float u = 0.f;
#pragma unroll
        for (int c2 = c; c2 < 9; ++c2) u = fmaf(g[idx++], ft[c2], u);
        t2 = fmaf(ft[c], u, t2);
        t1 = fmaf(ft[c], wsv[c], t1);
      }
      s1 += t1;
      s2 += t2;
      if (!has2) break;
      p = p2;
      f = f2;
      np = np2;
      cx = cx2;
      cy = cy2;
    }
  }
  red[wv][lane] = make_float2(s1, s2);
  __syncthreads();
  if (t < 64) {
    const float v = red[0][t].x + red[1][t].x + red[2][t].x + red[3][t].x;
    partials[((size_t)t * 2 + 0) * S1 + blockIdx.x] = v;
  } else if (t < 128) {
    const int n = t - 64;
    const float v = red[0][n].y + red[1][n].y + red[2][n].y + red[3][n].y;
    partials[((size_t)n * 2 + 1) * S1 + blockIdx.x] = v;
  }
}

// k2: reduce partials (coalesced), compute a[n], b[n]. One block per n.
__global__ __launch_bounds__(256) void k2_stats(
    const float* __restrict__ partials, const float* __restrict__ gamma,
    const float* __restrict__ beta, float* __restrict__ ab, int P) {
  const int n = blockIdx.x, t = threadIdx.x;
  __shared__ float r1[4], r2[4];
  const float* p1 = partials + ((size_t)n * 2 + 0) * S1;
  const float* p2 = partials + ((size_t)n * 2 + 1) * S1;
  float a1 = 0.f, a2 = 0.f;
  for (int b = t; b < S1; b += 256) {
    a1 += p1[b];
    a2 += p2[b];
  }
  a1 = wave_sum(a1);
  a2 = wave_sum(a2);
  const int wv = t >> 6;
  if ((t & 63) == 0) {
    r1[wv] = a1;
    r2[wv] = a2;
  }
  __syncthreads();
  if (t == 0) {
    const float v2 = r1[0] + r1[1] + r1[2] + r1[3];  // sum x
    const float v1 = r2[0] + r2[1] + r2[2] + r2[3];  // sum x^2
    const float invPN = 1.f / ((float)P * 64.f);
    const float mu = v2 * invPN;
    const float var = v1 * invPN - mu * mu;
    const float a = gamma[n] * rsqrtf(var + EPS_);
    const float b = beta[n] - mu * a;
    ab[n] = a;
    ab[64 + n] = b;
  }
}

// k4 (R17, unchanged): BN affine folded INTO the MFMA via bias channel.
// Lane packs its OWN row n=lane: A[n][k] = a_n*ft[k] (k<9, masked),
// A[n][9] = b_n; B[9][o] = 1.0 -> acc4[r] == y directly. Pure fmax
// epilogue; no shab LDS; no block barrier (A_lds is per-wave-owned).
// R19: launched TWICE (idempotent) as a timing probe: dur delta == k4+gap.
__global__ __launch_bounds__(256) void k4_mfma(
    const float* __restrict__ feats, const float* __restrict__ aux,
    const uint32_t* __restrict__ Bpack, const float* __restrict__ ab,
    float* __restrict__ out, int P) {
  __shared__ uint32_t A_lds[4][64][20];  // rows padded to 80 B
  const int t = threadIdx.x, lane = t & 63, wv = t >> 6;
  const int g16 = lane >> 4, l16 = lane & 15;

  uint4 bq[4];
#pragma unroll
  for (int nt = 0; nt < 4; ++nt)
    bq[nt] =
        *reinterpret_cast<const uint4*>(Bpack + ((size_t)nt * 64 + lane) * 4);
  const float a_l = ab[lane];       // BN scale for this lane's row n==lane
  const float b_l = ab[64 + lane];  // BN bias

  // zero the permanently-zero k-slots 5..15 of this wave's rows
  A_lds[wv][lane][5] = 0u;
  A_lds[wv][lane][6] = 0u;
  A_lds[wv][lane][7] = 0u;
  *reinterpret_cast<uint4*>(&A_lds[wv][lane][8]) = make_uint4(0u, 0u, 0u, 0u);
  *reinterpret_cast<uint4*>(&A_lds[wv][lane][12]) = make_uint4(0u, 0u, 0u, 0u);
  // no __syncthreads: each wave exclusively owns A_lds[wv]

  const int p = blockIdx.x * 4 + wv;
  if (p >= P) return;
  const float4 f =
      *reinterpret_cast<const float4*>(feats + (size_t)p * 256 + lane * 4);
  const float4 a0 = *reinterpret_cast<const float4*>(aux + (size_t)p * 8);
  const float4 a1 = *reinterpret_cast<const float4*>(aux + (size_t)p * 8 + 4);

  const float m0 = a0.x, m1 = a0.y, m2 = a0.z, ox = a0.w, oy = a1.x;
  const int np = __float_as_int(a1.y);
  const bool valid = lane < np;
  const float v0 = valid ? a_l * f.x : 0.f;
  const float v1 = valid ? a_l * f.y : 0.f;
  const float v2 = valid ? a_l * f.z : 0.f;
  const float v3 = valid ? a_l * f.w : 0.f;
  const float v4 = valid ? a_l * (f.x - m0) : 0.f;
  const float v5 = valid ? a_l * (f.y - m1) : 0.f;
  const float v6 = valid ? a_l * (f.z - m2) : 0.f;
  const float v7 = valid ? a_l * (f.x - ox) : 0.f;
  const float v8 = valid ? a_l * (f.y - oy) : 0.f;
  union {
    uint32_t u[6];
    uint4 q;
  } pk;
  pk.u[0] = cvtpk(v0, v1);
  pk.u[1] = cvtpk(v2, v3);
  pk.u[2] = cvtpk(v4, v5);
  pk.u[3] = cvtpk(v6, v7);
  pk.u[4] = cvtpk(v8, b_l);  // slot 9 = bias channel (always, even masked)
  // stage this lane's A row (lane == n); same-wave ds_write->ds_read is
  // in-order and each wave owns its A_lds[wv] region: no barrier needed.
  *reinterpret_cast<uint4*>(&A_lds[wv][lane][0]) = pk.q;
  A_lds[wv][lane][4] = pk.u[4];

  bf16x8 afr[4];
#pragma unroll
  for (int mt = 0; mt < 4; ++mt) {
    afr[mt] =
        *reinterpret_cast<const bf16x8*>(&A_lds[wv][mt * 16 + l16][g16 * 4]);
  }
  const f32x4 accz = {0.f, 0.f, 0.f, 0.f};
  float mx[4] = {0.f, 0.f, 0.f, 0.f};  // init 0 == fused relu
#pragma unroll
  for (int mt = 0; mt < 4; ++mt) {
    const bf16x8 a = afr[mt];
#pragma unroll
    for (int nt = 0; nt < 4; ++nt) {
      f32x4 acc4 = __builtin_amdgcn_mfma_f32_16x16x32_bf16(
          a, __builtin_bit_cast(bf16x8, bq[nt]), accz, 0, 0, 0);
#pragma unroll
      for (int r = 0; r < 4; ++r) mx[nt] = fmaxf(mx[nt], acc4[r]);
    }
  }
#pragma unroll
  for (int nt = 0; nt < 4; ++nt) {
    mx[nt] = fmaxf(mx[nt], __shfl_xor(mx[nt], 16));
    mx[nt] = fmaxf(mx[nt], __shfl_xor(mx[nt], 32));
  }
  const float outv =
      (g16 == 0) ? mx[0] : (g16 == 1) ? mx[1] : (g16 == 2) ? mx[2] : mx[3];
  out[(size_t)p * 64 + lane] = outv;  // o = g16*16 + l16 == lane
}

extern "C" void kernel_launch(void* const* d_in, const int* in_sizes, int n_in,
                              void* d_out, int out_size, void* d_ws,
                              size_t ws_size, hipStream_t stream) {
  const float* feats = (const float*)d_in[0];
  const int* npts = (const int*)d_in[1];
  const int* coors = (const int*)d_in[2];
  const float* W = (const float*)d_in[3];
  const float* gamma = (const float*)d_in[4];
  const float* beta = (const float*)d_in[5];
  float* out = (float*)d_out;
  float* ws = (float*)d_ws;

  const int P = in_sizes[1];  // num_points has P elements

  float* ab = ws;                              // [128]: a[64], b[64]
  uint32_t* Bpack = (uint32_t*)(ws + 128);     // [1024] u32 = 4x64 frags
  float* partials = ws + 128 + 1024;           // [64][2][S1]
  float* aux = partials + 64 * 2 * S1;         // [8*P]

  k1_moments<<<S1, 256, 0, stream>>>(feats, npts, coors, W, partials, aux,
                                     Bpack, P);
  k2_stats<<<64, 256, 0, stream>>>(partials, gamma, beta, ab, P);
  const int g1 = (P + 3) / 4;  // 4 waves/block, 1 pillar/wave
  // MEASUREMENT: k4 launched twice (idempotent, deterministic).
  // dur(R19) - dur(R17) == k4 + launch gap.
  k4_mfma<<<g1, 256, 0, stream>>>(feats, aux, Bpack, ab, out, P);
  k4_mfma<<<g1, 256, 0, stream>>>(feats, aux, Bpack, ab, out, P);
}

// Round 20
// 54.943 us; speedup vs baseline: 1.0059x; 1.0059x over previous
//
#include <hip/hip_runtime.h>
#include <hip/hip_bf16.h>
#include <math.h>

typedef __attribute__((ext_vector_type(8))) __bf16 bf16x8;
typedef __attribute__((ext_vector_type(4))) float f32x4;

constexpr float VX_ = 0.2f;
constexpr float VY_ = 0.2f;
constexpr float X_OFF_ = 0.1f;    // VX/2 + 0.0
constexpr float Y_OFF_ = -39.9f;  // VY/2 - 40.0
constexpr float EPS_ = 1e-3f;

#define S1 512  // k1 block count; partials = [64][2][S1]

__device__ __forceinline__ float wave_sum(float v) {
#pragma unroll
  for (int off = 32; off; off >>= 1) v += __shfl_xor(v, off);
  return v;
}

__device__ __forceinline__ ushort bf16bits(float x) {
  __hip_bfloat16 h = __float2bfloat16(x);
  return __builtin_bit_cast(ushort, h);
}

// packed RNE f32x2 -> bf16x2 (gfx950 has the instruction but no builtin)
__device__ __forceinline__ uint32_t cvtpk(float lo, float hi) {
  uint32_t r;
  asm("v_cvt_pk_bf16_f32 %0, %1, %2" : "=v"(r) : "v"(lo), "v"(hi));
  return r;
}

// k1: inline concurrent prep (W->LDS, G' = scaled W^T W + wsum) + per-n
// moments pre-contracted to 2 floats/thread + per-pillar aux
// {m0,m1,m2,ox,oy,np}. Non-atomic partials [(n*2+j)*S1 + block].
// Block 0 also packs the MFMA B fragments (B[9][o] = 1.0 bias channel).
// R20: launched TWICE (idempotent) as a timing probe: delta == k1 + gap.
__global__ __launch_bounds__(256) void k1_moments(
    const float* __restrict__ feats, const int* __restrict__ npts_arr,
    const int* __restrict__ coors, const float* __restrict__ W,
    float* __restrict__ partials, float* __restrict__ aux,
    uint32_t* __restrict__ Bpack, int P) {
  __shared__ float W_lds[576];
  __shared__ float gws[54];  // G'[45] (off-diag doubled) + wsum[9]
  __shared__ float2 red[4][64];
  const int t = threadIdx.x, lane = t & 63, wv = t >> 6;

  for (int i = t; i < 576; i += 256) W_lds[i] = W[i];
  __syncthreads();
  if (t < 180) {  // G': 45 pairs x 4-way split over o
    const int pr = t >> 2, k = t & 3;
    int c = 0, rem = pr;
    while (rem >= 9 - c) {
      rem -= 9 - c;
      ++c;
    }
    const int c2 = c + rem;
    float s = 0.f;
    for (int o = k * 16; o < k * 16 + 16; ++o)
      s += W_lds[o * 9 + c] * W_lds[o * 9 + c2];
    s += __shfl_xor(s, 1);
    s += __shfl_xor(s, 2);
    if (k == 0) gws[pr] = (c == c2) ? s : 2.f * s;
  } else if (t < 216) {  // wsum: 9 cols x 4-way split
    const int tt = t - 180, c = tt >> 2, k = tt & 3;
    float s = 0.f;
    for (int o = k * 16; o < k * 16 + 16; ++o) s += W_lds[o * 9 + c];
    s += __shfl_xor(s, 1);
    s += __shfl_xor(s, 2);
    if (k == 0) gws[45 + c] = s;
  }
  __syncthreads();
  float g[45], wsv[9];
#pragma unroll
  for (int i = 0; i < 45; ++i) g[i] = gws[i];
#pragma unroll
  for (int i = 0; i < 9; ++i) wsv[i] = gws[45 + i];

  if (blockIdx.x == 0) {  // Bpack build; kk==9 -> 1.0 (bias channel)
    const int nt = t >> 6, bl = t & 63;
    const int l16 = bl & 15, g16 = bl >> 4;
    const int col = nt * 16 + l16;
    ushort h[8];
#pragma unroll
    for (int j = 0; j < 8; ++j) {
      const int kk = 8 * g16 + j;
      h[j] = (kk < 9) ? bf16bits(W_lds[col * 9 + kk])
                      : ((kk == 9) ? bf16bits(1.0f) : (ushort)0);
    }
    uint4 q;
    q.x = (uint)h[0] | ((uint)h[1] << 16);
    q.y = (uint)h[2] | ((uint)h[3] << 16);
    q.z = (uint)h[4] | ((uint)h[5] << 16);
    q.w = (uint)h[6] | ((uint)h[7] << 16);
    *reinterpret_cast<uint4*>(Bpack + (size_t)t * 4) = q;
  }

  float s1 = 0.f, s2 = 0.f;
  const int nw = S1 * 4;
  int p = blockIdx.x * 4 + wv;
  if (p < P) {
    float4 f =
        *reinterpret_cast<const float4*>(feats + (size_t)p * 256 + lane * 4);
    int np = npts_arr[p];
    int cx = coors[p * 4 + 3], cy = coors[p * 4 + 2];
    while (true) {
      const int p2 = p + nw;
      const bool has2 = p2 < P;
      float4 f2 = make_float4(0.f, 0.f, 0.f, 0.f);
      int np2 = 1, cx2 = 0, cy2 = 0;
      if (has2) {  // prefetch next pillar
        f2 = *reinterpret_cast<const float4*>(feats + (size_t)p2 * 256 +
                                              lane * 4);
        np2 = npts_arr[p2];
        cx2 = coors[p2 * 4 + 3];
        cy2 = coors[p2 * 4 + 2];
      }
      const float ox = (float)cx * VX_ + X_OFF_;
      const float oy = (float)cy * VY_ + Y_OFF_;
      const float inv = 1.f / (float)np;
      const float m0 = wave_sum(f.x) * inv;
      const float m1 = wave_sum(f.y) * inv;
      const float m2 = wave_sum(f.z) * inv;
      if (lane == 0) {  // per-pillar aux for k4 (fire-and-forget stores)
        *reinterpret_cast<float4*>(aux + (size_t)p * 8) =
            make_float4(m0, m1, m2, ox);
        *reinterpret_cast<float4*>(aux + (size_t)p * 8 + 4) =
            make_float4(oy, __int_as_float(np), 0.f, 0.f);
      }
      const bool valid = lane < np;
      float ft[9] = {f.x,      f.y,      f.z,      f.w,      f.x - m0,
                     f.y - m1, f.z - m2, f.x - ox, f.y - oy};
#pragma unroll
      for (int c = 0; c < 9; ++c) ft[c] = valid ? ft[c] : 0.f;
      int idx = 0;
      float t1 = 0.f, t2 = 0.f;
#pragma unroll
      for (int c = 0; c < 9; ++c) {
        float u = 0.f;
#pragma unroll
        for (int c2 = c; c2 < 9; ++c2) u = fmaf(g[idx++], ft[c2], u);
        t2 = fmaf(ft[c], u, t2);
        t1 = fmaf(ft[c], wsv[c], t1);
      }
      s1 += t1;
      s2 += t2;
      if (!has2) break;
      p = p2;
      f = f2;
      np = np2;
      cx = cx2;
      cy = cy2;
    }
  }
  red[wv][lane] = make_float2(s1, s2);
  __syncthreads();
  if (t < 64) {
    const float v = red[0][t].x + red[1][t].x + red[2][t].x + red[3][t].x;
    partials[((size_t)t * 2 + 0) * S1 + blockIdx.x] = v;
  } else if (t < 128) {
    const int n = t - 64;
    const float v = red[0][n].y + red[1][n].y + red[2][n].y + red[3][n].y;
    partials[((size_t)n * 2 + 1) * S1 + blockIdx.x] = v;
  }
}

// k2: reduce partials (coalesced), compute a[n], b[n]. One block per n.
__global__ __launch_bounds__(256) void k2_stats(
    const float* __restrict__ partials, const float* __restrict__ gamma,
    const float* __restrict__ beta, float* __restrict__ ab, int P) {
  const int n = blockIdx.x, t = threadIdx.x;
  __shared__ float r1[4], r2[4];
  const float* p1 = partials + ((size_t)n * 2 + 0) * S1;
  const float* p2 = partials + ((size_t)n * 2 + 1) * S1;
  float a1 = 0.f, a2 = 0.f;
  for (int b = t; b < S1; b += 256) {
    a1 += p1[b];
    a2 += p2[b];
  }
  a1 = wave_sum(a1);
  a2 = wave_sum(a2);
  const int wv = t >> 6;
  if ((t & 63) == 0) {
    r1[wv] = a1;
    r2[wv] = a2;
  }
  __syncthreads();
  if (t == 0) {
    const float v2 = r1[0] + r1[1] + r1[2] + r1[3];  // sum x
    const float v1 = r2[0] + r2[1] + r2[2] + r2[3];  // sum x^2
    const float invPN = 1.f / ((float)P * 64.f);
    const float mu = v2 * invPN;
    const float var = v1 * invPN - mu * mu;
    const float a = gamma[n] * rsqrtf(var + EPS_);
    const float b = beta[n] - mu * a;
    ab[n] = a;
    ab[64 + n] = b;
  }
}

// k4 (R17, unchanged): BN affine folded INTO the MFMA via bias channel.
// Lane packs its OWN row n=lane: A[n][k] = a_n*ft[k] (k<9, masked),
// A[n][9] = b_n; B[9][o] = 1.0 -> acc4[r] == y directly. Pure fmax
// epilogue; no shab LDS; no block barrier (A_lds is per-wave-owned).
__global__ __launch_bounds__(256) void k4_mfma(
    const float* __restrict__ feats, const float* __restrict__ aux,
    const uint32_t* __restrict__ Bpack, const float* __restrict__ ab,
    float* __restrict__ out, int P) {
  __shared__ uint32_t A_lds[4][64][20];  // rows padded to 80 B
  const int t = threadIdx.x, lane = t & 63, wv = t >> 6;
  const int g16 = lane >> 4, l16 = lane & 15;

  uint4 bq[4];
#pragma unroll
  for (int nt = 0; nt < 4; ++nt)
    bq[nt] =
        *reinterpret_cast<const uint4*>(Bpack + ((size_t)nt * 64 + lane) * 4);
  const float a_l = ab[lane];       // BN scale for this lane's row n==lane
  const float b_l = ab[64 + lane];  // BN bias

  // zero the permanently-zero k-slots 5..15 of this wave's rows
  A_lds[wv][lane][5] = 0u;
  A_lds[wv][lane][6] = 0u;
  A_lds[wv][lane][7] = 0u;
  *reinterpret_cast<uint4*>(&A_lds[wv][lane][8]) = make_uint4(0u, 0u, 0u, 0u);
  *reinterpret_cast<uint4*>(&A_lds[wv][lane][12]) = make_uint4(0u, 0u, 0u, 0u);
  // no __syncthreads: each wave exclusively owns A_lds[wv]

  const int p = blockIdx.x * 4 + wv;
  if (p >= P) return;
  const float4 f =
      *reinterpret_cast<const float4*>(feats + (size_t)p * 256 + lane * 4);
  const float4 a0 = *reinterpret_cast<const float4*>(aux + (size_t)p * 8);
  const float4 a1 = *reinterpret_cast<const float4*>(aux + (size_t)p * 8 + 4);

  const float m0 = a0.x, m1 = a0.y, m2 = a0.z, ox = a0.w, oy = a1.x;
  const int np = __float_as_int(a1.y);
  const bool valid = lane < np;
  const float v0 = valid ? a_l * f.x : 0.f;
  const float v1 = valid ? a_l * f.y : 0.f;
  const float v2 = valid ? a_l * f.z : 0.f;
  const float v3 = valid ? a_l * f.w : 0.f;
  const float v4 = valid ? a_l * (f.x - m0) : 0.f;
  const float v5 = valid ? a_l * (f.y - m1) : 0.f;
  const float v6 = valid ? a_l * (f.z - m2) : 0.f;
  const float v7 = valid ? a_l * (f.x - ox) : 0.f;
  const float v8 = valid ? a_l * (f.y - oy) : 0.f;
  union {
    uint32_t u[6];
    uint4 q;
  } pk;
  pk.u[0] = cvtpk(v0, v1);
  pk.u[1] = cvtpk(v2, v3);
  pk.u[2] = cvtpk(v4, v5);
  pk.u[3] = cvtpk(v6, v7);
  pk.u[4] = cvtpk(v8, b_l);  // slot 9 = bias channel (always, even masked)
  // stage this lane's A row (lane == n); same-wave ds_write->ds_read is
  // in-order and each wave owns its A_lds[wv] region: no barrier needed.
  *reinterpret_cast<uint4*>(&A_lds[wv][lane][0]) = pk.q;
  A_lds[wv][lane][4] = pk.u[4];

  bf16x8 afr[4];
#pragma unroll
  for (int mt = 0; mt < 4; ++mt) {
    afr[mt] =
        *reinterpret_cast<const bf16x8*>(&A_lds[wv][mt * 16 + l16][g16 * 4]);
  }
  const f32x4 accz = {0.f, 0.f, 0.f, 0.f};
  float mx[4] = {0.f, 0.f, 0.f, 0.f};  // init 0 == fused relu
#pragma unroll
  for (int mt = 0; mt < 4; ++mt) {
    const bf16x8 a = afr[mt];
#pragma unroll
    for (int nt = 0; nt < 4; ++nt) {
      f32x4 acc4 = __builtin_amdgcn_mfma_f32_16x16x32_bf16(
          a, __builtin_bit_cast(bf16x8, bq[nt]), accz, 0, 0, 0);
#pragma unroll
      for (int r = 0; r < 4; ++r) mx[nt] = fmaxf(mx[nt], acc4[r]);
    }
  }
#pragma unroll
  for (int nt = 0; nt < 4; ++nt) {
    mx[nt] = fmaxf(mx[nt], __shfl_xor(mx[nt], 16));
    mx[nt] = fmaxf(mx[nt], __shfl_xor(mx[nt], 32));
  }
  const float outv =
      (g16 == 0) ? mx[0] : (g16 == 1) ? mx[1] : (g16 == 2) ? mx[2] : mx[3];
  out[(size_t)p * 64 + lane] = outv;  // o = g16*16 + l16 == lane
}

extern "C" void kernel_launch(void* const* d_in, const int* in_sizes, int n_in,
                              void* d_out, int out_size, void* d_ws,
                              size_t ws_size, hipStream_t stream) {
  const float* feats = (const float*)d_in[0];
  const int* npts = (const int*)d_in[1];
  const int* coors = (const int*)d_in[2];
  const float* W = (const float*)d_in[3];
  const float* gamma = (const float*)d_in[4];
  const float* beta = (const float*)d_in[5];
  float* out = (float*)d_out;
  float* ws = (float*)d_ws;

  const int P = in_sizes[1];  // num_points has P elements

  float* ab = ws;                              // [128]: a[64], b[64]
  uint32_t* Bpack = (uint32_t*)(ws + 128);     // [1024] u32 = 4x64 frags
  float* partials = ws + 128 + 1024;           // [64][2][S1]
  float* aux = partials + 64 * 2 * S1;         // [8*P]

  // MEASUREMENT: k1 launched twice (idempotent, deterministic).
  // dur(R20) - dur(R17) == k1 + launch gap.
  k1_moments<<<S1, 256, 0, stream>>>(feats, npts, coors, W, partials, aux,
                                     Bpack, P);
  k1_moments<<<S1, 256, 0, stream>>>(feats, npts, coors, W, partials, aux,
                                     Bpack, P);
  k2_stats<<<64, 256, 0, stream>>>(partials, gamma, beta, ab, P);
  const int g1 = (P + 3) / 4;  // 4 waves/block, 1 pillar/wave
  k4_mfma<<<g1, 256, 0, stream>>>(feats, aux, Bpack, ab, out, P);
}

// Round 21
// 41.102 us; speedup vs baseline: 1.3447x; 1.3368x over previous
//
#include <hip/hip_runtime.h>
#include <hip/hip_bf16.h>
#include <math.h>

typedef __attribute__((ext_vector_type(8))) __bf16 bf16x8;
typedef __attribute__((ext_vector_type(4))) float f32x4;

constexpr float VX_ = 0.2f;
constexpr float VY_ = 0.2f;
constexpr float X_OFF_ = 0.1f;    // VX/2 + 0.0
constexpr float Y_OFF_ = -39.9f;  // VY/2 - 40.0
constexpr float EPS_ = 1e-3f;

#define S1 512  // k1 block count; partials = [64][2][S1]

__device__ __forceinline__ float wave_sum(float v) {
#pragma unroll
  for (int off = 32; off; off >>= 1) v += __shfl_xor(v, off);
  return v;
}

__device__ __forceinline__ ushort bf16bits(float x) {
  __hip_bfloat16 h = __float2bfloat16(x);
  return __builtin_bit_cast(ushort, h);
}

// packed RNE f32x2 -> bf16x2 (gfx950 has the instruction but no builtin)
__device__ __forceinline__ uint32_t cvtpk(float lo, float hi) {
  uint32_t r;
  asm("v_cvt_pk_bf16_f32 %0, %1, %2" : "=v"(r) : "v"(lo), "v"(hi));
  return r;
}

// k1: inline concurrent prep (W->LDS, G' = scaled W^T W + wsum) + per-n
// moments pre-contracted to 2 floats/thread + per-pillar aux
// {m0,m1,m2,ox,oy,np}. Non-atomic partials [(n*2+j)*S1 + block].
// Block 0 also packs the MFMA B fragments (B[9][o] = 1.0 bias channel).
__global__ __launch_bounds__(256) void k1_moments(
    const float* __restrict__ feats, const int* __restrict__ npts_arr,
    const int* __restrict__ coors, const float* __restrict__ W,
    float* __restrict__ partials, float* __restrict__ aux,
    uint32_t* __restrict__ Bpack, int P) {
  __shared__ float W_lds[576];
  __shared__ float gws[54];  // G'[45] (off-diag doubled) + wsum[9]
  __shared__ float2 red[4][64];
  const int t = threadIdx.x, lane = t & 63, wv = t >> 6;

  for (int i = t; i < 576; i += 256) W_lds[i] = W[i];
  __syncthreads();
  if (t < 180) {  // G': 45 pairs x 4-way split over o
    const int pr = t >> 2, k = t & 3;
    int c = 0, rem = pr;
    while (rem >= 9 - c) {
      rem -= 9 - c;
      ++c;
    }
    const int c2 = c + rem;
    float s = 0.f;
    for (int o = k * 16; o < k * 16 + 16; ++o)
      s += W_lds[o * 9 + c] * W_lds[o * 9 + c2];
    s += __shfl_xor(s, 1);
    s += __shfl_xor(s, 2);
    if (k == 0) gws[pr] = (c == c2) ? s : 2.f * s;
  } else if (t < 216) {  // wsum: 9 cols x 4-way split
    const int tt = t - 180, c = tt >> 2, k = tt & 3;
    float s = 0.f;
    for (int o = k * 16; o < k * 16 + 16; ++o) s += W_lds[o * 9 + c];
    s += __shfl_xor(s, 1);
    s += __shfl_xor(s, 2);
    if (k == 0) gws[45 + c] = s;
  }
  __syncthreads();
  float g[45], wsv[9];
#pragma unroll
  for (int i = 0; i < 45; ++i) g[i] = gws[i];
#pragma unroll
  for (int i = 0; i < 9; ++i) wsv[i] = gws[45 + i];

  if (blockIdx.x == 0) {  // Bpack build; kk==9 -> 1.0 (bias channel)
    const int nt = t >> 6, bl = t & 63;
    const int l16 = bl & 15, g16 = bl >> 4;
    const int col = nt * 16 + l16;
    ushort h[8];
#pragma unroll
    for (int j = 0; j < 8; ++j) {
      const int kk = 8 * g16 + j;
      h[j] = (kk < 9) ? bf16bits(W_lds[col * 9 + kk])
                      : ((kk == 9) ? bf16bits(1.0f) : (ushort)0);
    }
    uint4 q;
    q.x = (uint)h[0] | ((uint)h[1] << 16);
    q.y = (uint)h[2] | ((uint)h[3] << 16);
    q.z = (uint)h[4] | ((uint)h[5] << 16);
    q.w = (uint)h[6] | ((uint)h[7] << 16);
    *reinterpret_cast<uint4*>(Bpack + (size_t)t * 4) = q;
  }

  float s1 = 0.f, s2 = 0.f;
  const int nw = S1 * 4;
  int p = blockIdx.x * 4 + wv;
  if (p < P) {
    float4 f =
        *reinterpret_cast<const float4*>(feats + (size_t)p * 256 + lane * 4);
    int np = npts_arr[p];
    int cx = coors[p * 4 + 3], cy = coors[p * 4 + 2];
    while (true) {
      const int p2 = p + nw;
      const bool has2 = p2 < P;
      float4 f2 = make_float4(0.f, 0.f, 0.f, 0.f);
      int np2 = 1, cx2 = 0, cy2 = 0;
      if (has2) {  // prefetch next pillar
        f2 = *reinterpret_cast<const float4*>(feats + (size_t)p2 * 256 +
                                              lane * 4);
        np2 = npts_arr[p2];
        cx2 = coors[p2 * 4 + 3];
        cy2 = coors[p2 * 4 + 2];
      }
      const float ox = (float)cx * VX_ + X_OFF_;
      const float oy = (float)cy * VY_ + Y_OFF_;
      const float inv = 1.f / (float)np;
      const float m0 = wave_sum(f.x) * inv;
      const float m1 = wave_sum(f.y) * inv;
      const float m2 = wave_sum(f.z) * inv;
      if (lane == 0) {  // per-pillar aux for k4 (fire-and-forget stores)
        *reinterpret_cast<float4*>(aux + (size_t)p * 8) =
            make_float4(m0, m1, m2, ox);
        *reinterpret_cast<float4*>(aux + (size_t)p * 8 + 4) =
            make_float4(oy, __int_as_float(np), 0.f, 0.f);
      }
      const bool valid = lane < np;
      float ft[9] = {f.x,      f.y,      f.z,      f.w,      f.x - m0,
                     f.y - m1, f.z - m2, f.x - ox, f.y - oy};
#pragma unroll
      for (int c = 0; c < 9; ++c) ft[c] = valid ? ft[c] : 0.f;
      int idx = 0;
      float t1 = 0.f, t2 = 0.f;
#pragma unroll
      for (int c = 0; c < 9; ++c) {
        float u = 0.f;
#pragma unroll
        for (int c2 = c; c2 < 9; ++c2) u = fmaf(g[idx++], ft[c2], u);
        t2 = fmaf(ft[c], u, t2);
        t1 = fmaf(ft[c], wsv[c], t1);
      }
      s1 += t1;
      s2 += t2;
      if (!has2) break;
      p = p2;
      f = f2;
      np = np2;
      cx = cx2;
      cy = cy2;
    }
  }
  red[wv][lane] = make_float2(s1, s2);
  __syncthreads();
  if (t < 64) {
    const float v = red[0][t].x + red[1][t].x + red[2][t].x + red[3][t].x;
    partials[((size_t)t * 2 + 0) * S1 + blockIdx.x] = v;
  } else if (t < 128) {
    const int n = t - 64;
    const float v = red[0][n].y + red[1][n].y + red[2][n].y + red[3][n].y;
    partials[((size_t)n * 2 + 1) * S1 + blockIdx.x] = v;
  }
}

// k2: reduce partials (coalesced), compute a[n], b[n]. One block per n.
__global__ __launch_bounds__(256) void k2_stats(
    const float* __restrict__ partials, const float* __restrict__ gamma,
    const float* __restrict__ beta, float* __restrict__ ab, int P) {
  const int n = blockIdx.x, t = threadIdx.x;
  __shared__ float r1[4], r2[4];
  const float* p1 = partials + ((size_t)n * 2 + 0) * S1;
  const float* p2 = partials + ((size_t)n * 2 + 1) * S1;
  float a1 = 0.f, a2 = 0.f;
  for (int b = t; b < S1; b += 256) {
    a1 += p1[b];
    a2 += p2[b];
  }
  a1 = wave_sum(a1);
  a2 = wave_sum(a2);
  const int wv = t >> 6;
  if ((t & 63) == 0) {
    r1[wv] = a1;
    r2[wv] = a2;
  }
  __syncthreads();
  if (t == 0) {
    const float v2 = r1[0] + r1[1] + r1[2] + r1[3];  // sum x
    const float v1 = r2[0] + r2[1] + r2[2] + r2[3];  // sum x^2
    const float invPN = 1.f / ((float)P * 64.f);
    const float mu = v2 * invPN;
    const float var = v1 * invPN - mu * mu;
    const float a = gamma[n] * rsqrtf(var + EPS_);
    const float b = beta[n] - mu * a;
    ab[n] = a;
    ab[64 + n] = b;
  }
}

// k4 (R21): R17's bias-fold body + R12's 4-pillars-per-wave loop, so the
// per-block prologue (Bpack, ab, LDS zeroing) is amortized 4x and block
// count drops 7500 -> 1875. A[n][k] = a_n*ft[k] (k<9), A[n][9] = b_n,
// B[9][o] = 1.0 -> acc4[r] == y directly; pure fmax epilogue.
__global__ __launch_bounds__(256) void k4_mfma(
    const float* __restrict__ feats, const float* __restrict__ aux,
    const uint32_t* __restrict__ Bpack, const float* __restrict__ ab,
    float* __restrict__ out, int P) {
  __shared__ uint32_t A_lds[4][64][20];  // rows padded to 80 B
  const int t = threadIdx.x, lane = t & 63, wv = t >> 6;
  const int g16 = lane >> 4, l16 = lane & 15;

  uint4 bq[4];
#pragma unroll
  for (int nt = 0; nt < 4; ++nt)
    bq[nt] =
        *reinterpret_cast<const uint4*>(Bpack + ((size_t)nt * 64 + lane) * 4);
  const float a_l = ab[lane];       // BN scale for this lane's row n==lane
  const float b_l = ab[64 + lane];  // BN bias

  // zero the permanently-zero k-slots 5..15 of this wave's rows (once)
  A_lds[wv][lane][5] = 0u;
  A_lds[wv][lane][6] = 0u;
  A_lds[wv][lane][7] = 0u;
  *reinterpret_cast<uint4*>(&A_lds[wv][lane][8]) = make_uint4(0u, 0u, 0u, 0u);
  *reinterpret_cast<uint4*>(&A_lds[wv][lane][12]) = make_uint4(0u, 0u, 0u, 0u);
  // no __syncthreads: each wave exclusively owns A_lds[wv]

  const int stride = gridDim.x * 4;
  int p = blockIdx.x * 4 + wv;
  if (p >= P) return;
  float4 f = *reinterpret_cast<const float4*>(feats + (size_t)p * 256 + lane * 4);
  float4 a0 = *reinterpret_cast<const float4*>(aux + (size_t)p * 8);
  float4 a1 = *reinterpret_cast<const float4*>(aux + (size_t)p * 8 + 4);
  while (true) {
    const int p2 = p + stride;
    const bool has2 = p2 < P;
    float4 f2 = make_float4(0.f, 0.f, 0.f, 0.f);
    float4 a0b = make_float4(0.f, 0.f, 0.f, 0.f);
    float4 a1b = make_float4(0.f, 0.f, 0.f, 0.f);
    if (has2) {  // prefetch next pillar (feat row + aux)
      f2 = *reinterpret_cast<const float4*>(feats + (size_t)p2 * 256 + lane * 4);
      a0b = *reinterpret_cast<const float4*>(aux + (size_t)p2 * 8);
      a1b = *reinterpret_cast<const float4*>(aux + (size_t)p2 * 8 + 4);
    }
    const float m0 = a0.x, m1 = a0.y, m2 = a0.z, ox = a0.w, oy = a1.x;
    const int np = __float_as_int(a1.y);
    const bool valid = lane < np;
    const float v0 = valid ? a_l * f.x : 0.f;
    const float v1 = valid ? a_l * f.y : 0.f;
    const float v2 = valid ? a_l * f.z : 0.f;
    const float v3 = valid ? a_l * f.w : 0.f;
    const float v4 = valid ? a_l * (f.x - m0) : 0.f;
    const float v5 = valid ? a_l * (f.y - m1) : 0.f;
    const float v6 = valid ? a_l * (f.z - m2) : 0.f;
    const float v7 = valid ? a_l * (f.x - ox) : 0.f;
    const float v8 = valid ? a_l * (f.y - oy) : 0.f;
    union {
      uint32_t u[6];
      uint4 q;
    } pk;
    pk.u[0] = cvtpk(v0, v1);
    pk.u[1] = cvtpk(v2, v3);
    pk.u[2] = cvtpk(v4, v5);
    pk.u[3] = cvtpk(v6, v7);
    pk.u[4] = cvtpk(v8, b_l);  // slot 9 = bias channel (always, even masked)
    // stage this lane's A row (lane == n); same-wave ds_write->ds_read is
    // in-order and each wave owns its A_lds[wv] region: no barrier needed.
    *reinterpret_cast<uint4*>(&A_lds[wv][lane][0]) = pk.q;
    A_lds[wv][lane][4] = pk.u[4];

    bf16x8 afr[4];
#pragma unroll
    for (int mt = 0; mt < 4; ++mt) {
      afr[mt] =
          *reinterpret_cast<const bf16x8*>(&A_lds[wv][mt * 16 + l16][g16 * 4]);
    }
    const f32x4 accz = {0.f, 0.f, 0.f, 0.f};
    float mx[4] = {0.f, 0.f, 0.f, 0.f};  // init 0 == fused relu
#pragma unroll
    for (int mt = 0; mt < 4; ++mt) {
      const bf16x8 a = afr[mt];
#pragma unroll
      for (int nt = 0; nt < 4; ++nt) {
        f32x4 acc4 = __builtin_amdgcn_mfma_f32_16x16x32_bf16(
            a, __builtin_bit_cast(bf16x8, bq[nt]), accz, 0, 0, 0);
#pragma unroll
        for (int r = 0; r < 4; ++r) mx[nt] = fmaxf(mx[nt], acc4[r]);
      }
    }
#pragma unroll
    for (int nt = 0; nt < 4; ++nt) {
      mx[nt] = fmaxf(mx[nt], __shfl_xor(mx[nt], 16));
      mx[nt] = fmaxf(mx[nt], __shfl_xor(mx[nt], 32));
    }
    const float outv =
        (g16 == 0) ? mx[0] : (g16 == 1) ? mx[1] : (g16 == 2) ? mx[2] : mx[3];
    out[(size_t)p * 64 + lane] = outv;  // o = g16*16 + l16 == lane
    if (!has2) break;
    p = p2;
    f = f2;
    a0 = a0b;
    a1 = a1b;
  }
}

extern "C" void kernel_launch(void* const* d_in, const int* in_sizes, int n_in,
                              void* d_out, int out_size, void* d_ws,
                              size_t ws_size, hipStream_t stream) {
  const float* feats = (const float*)d_in[0];
  const int* npts = (const int*)d_in[1];
  const int* coors = (const int*)d_in[2];
  const float* W = (const float*)d_in[3];
  const float* gamma = (const float*)d_in[4];
  const float* beta = (const float*)d_in[5];
  float* out = (float*)d_out;
  float* ws = (float*)d_ws;

  const int P = in_sizes[1];  // num_points has P elements

  float* ab = ws;                              // [128]: a[64], b[64]
  uint32_t* Bpack = (uint32_t*)(ws + 128);     // [1024] u32 = 4x64 frags
  float* partials = ws + 128 + 1024;           // [64][2][S1]
  float* aux = partials + 64 * 2 * S1;         // [8*P]

  k1_moments<<<S1, 256, 0, stream>>>(feats, npts, coors, W, partials, aux,
                                     Bpack, P);
  k2_stats<<<64, 256, 0, stream>>>(partials, gamma, beta, ab, P);
  const int g4 = (P + 15) / 16;  // 4 waves/block, ~4 pillars/wave
  k4_mfma<<<g4, 256, 0, stream>>>(feats, aux, Bpack, ab, out, P);
}

// Round 22
// 40.303 us; speedup vs baseline: 1.3713x; 1.0198x over previous
//
#include <hip/hip_runtime.h>
#include <hip/hip_bf16.h>
#include <math.h>

typedef __attribute__((ext_vector_type(8))) __bf16 bf16x8;
typedef __attribute__((ext_vector_type(4))) float f32x4;

constexpr float VX_ = 0.2f;
constexpr float VY_ = 0.2f;
constexpr float X_OFF_ = 0.1f;    // VX/2 + 0.0
constexpr float Y_OFF_ = -39.9f;  // VY/2 - 40.0
constexpr float EPS_ = 1e-3f;

#define S1 512  // k1 block count; partials = [64][2][S1]

__device__ __forceinline__ float wave_sum(float v) {  // butterfly (k2 only)
#pragma unroll
  for (int off = 32; off; off >>= 1) v += __shfl_xor(v, off);
  return v;
}

// DPP add step: x += dpp_permuted(x). On-device validated in R18 (passed).
template <int CTRL, int RMASK>
__device__ __forceinline__ float dpp_add(float x) {
  const int xi = __builtin_bit_cast(int, x);
  const int yi = __builtin_amdgcn_update_dpp(0, xi, CTRL, RMASK, 0xf, false);
  return x + __builtin_bit_cast(float, yi);
}

// Full 64-lane sum via DPP (VALU pipe, zero LDS ops), broadcast via SGPR.
__device__ __forceinline__ float wave_sum_dpp(float v) {
  v = dpp_add<0x111, 0xf>(v);  // row_shr:1
  v = dpp_add<0x112, 0xf>(v);  // row_shr:2
  v = dpp_add<0x114, 0xf>(v);  // row_shr:4
  v = dpp_add<0x118, 0xf>(v);  // row_shr:8
  v = dpp_add<0x142, 0xa>(v);  // row_bcast:15 into rows 1,3
  v = dpp_add<0x143, 0xc>(v);  // row_bcast:31 into rows 2,3
  return __builtin_bit_cast(
      float, __builtin_amdgcn_readlane(__builtin_bit_cast(int, v), 63));
}

__device__ __forceinline__ ushort bf16bits(float x) {
  __hip_bfloat16 h = __float2bfloat16(x);
  return __builtin_bit_cast(ushort, h);
}

// packed RNE f32x2 -> bf16x2 (gfx950 has the instruction but no builtin)
__device__ __forceinline__ uint32_t cvtpk(float lo, float hi) {
  uint32_t r;
  asm("v_cvt_pk_bf16_f32 %0, %1, %2" : "=v"(r) : "v"(lo), "v"(hi));
  return r;
}

// k1: inline concurrent prep (W->LDS, G' = scaled W^T W + wsum) + per-n
// moments pre-contracted to 2 floats/thread + per-pillar aux
// {m0,m1,m2,ox,oy,np}. Non-atomic partials [(n*2+j)*S1 + block].
// Block 0 also packs the MFMA B fragments (B[9][o] = 1.0 bias channel).
// R22: wave sums via DPP (VALU pipe) — frees the LDS pipe in the hot loop.
__global__ __launch_bounds__(256) void k1_moments(
    const float* __restrict__ feats, const int* __restrict__ npts_arr,
    const int* __restrict__ coors, const float* __restrict__ W,
    float* __restrict__ partials, float* __restrict__ aux,
    uint32_t* __restrict__ Bpack, int P) {
  __shared__ float W_lds[576];
  __shared__ float gws[54];  // G'[45] (off-diag doubled) + wsum[9]
  __shared__ float2 red[4][64];
  const int t = threadIdx.x, lane = t & 63, wv = t >> 6;

  for (int i = t; i < 576; i += 256) W_lds[i] = W[i];
  __syncthreads();
  if (t < 180) {  // G': 45 pairs x 4-way split over o
    const int pr = t >> 2, k = t & 3;
    int c = 0, rem = pr;
    while (rem >= 9 - c) {
      rem -= 9 - c;
      ++c;
    }
    const int c2 = c + rem;
    float s = 0.f;
    for (int o = k * 16; o < k * 16 + 16; ++o)
      s += W_lds[o * 9 + c] * W_lds[o * 9 + c2];
    s += __shfl_xor(s, 1);
    s += __shfl_xor(s, 2);
    if (k == 0) gws[pr] = (c == c2) ? s : 2.f * s;
  } else if (t < 216) {  // wsum: 9 cols x 4-way split
    const int tt = t - 180, c = tt >> 2, k = tt & 3;
    float s = 0.f;
    for (int o = k * 16; o < k * 16 + 16; ++o) s += W_lds[o * 9 + c];
    s += __shfl_xor(s, 1);
    s += __shfl_xor(s, 2);
    if (k == 0) gws[45 + c] = s;
  }
  __syncthreads();
  float g[45], wsv[9];
#pragma unroll
  for (int i = 0; i < 45; ++i) g[i] = gws[i];
#pragma unroll
  for (int i = 0; i < 9; ++i) wsv[i] = gws[45 + i];

  if (blockIdx.x == 0) {  // Bpack build; kk==9 -> 1.0 (bias channel)
    const int nt = t >> 6, bl = t & 63;
    const int l16 = bl & 15, g16 = bl >> 4;
    const int col = nt * 16 + l16;
    ushort h[8];
#pragma unroll
    for (int j = 0; j < 8; ++j) {
      const int kk = 8 * g16 + j;
      h[j] = (kk < 9) ? bf16bits(W_lds[col * 9 + kk])
                      : ((kk == 9) ? bf16bits(1.0f) : (ushort)0);
    }
    uint4 q;
    q.x = (uint)h[0] | ((uint)h[1] << 16);
    q.y = (uint)h[2] | ((uint)h[3] << 16);
    q.z = (uint)h[4] | ((uint)h[5] << 16);
    q.w = (uint)h[6] | ((uint)h[7] << 16);
    *reinterpret_cast<uint4*>(Bpack + (size_t)t * 4) = q;
  }

  float s1 = 0.f, s2 = 0.f;
  const int nw = S1 * 4;
  int p = blockIdx.x * 4 + wv;
  if (p < P) {
    float4 f =
        *reinterpret_cast<const float4*>(feats + (size_t)p * 256 + lane * 4);
    int np = npts_arr[p];
    int cx = coors[p * 4 + 3], cy = coors[p * 4 + 2];
    while (true) {
      const int p2 = p + nw;
      const bool has2 = p2 < P;
      float4 f2 = make_float4(0.f, 0.f, 0.f, 0.f);
      int np2 = 1, cx2 = 0, cy2 = 0;
      if (has2) {  // prefetch next pillar
        f2 = *reinterpret_cast<const float4*>(feats + (size_t)p2 * 256 +
                                              lane * 4);
        np2 = npts_arr[p2];
        cx2 = coors[p2 * 4 + 3];
        cy2 = coors[p2 * 4 + 2];
      }
      const float ox = (float)cx * VX_ + X_OFF_;
      const float oy = (float)cy * VY_ + Y_OFF_;
      const float inv = 1.f / (float)np;
      const float m0 = wave_sum_dpp(f.x) * inv;
      const float m1 = wave_sum_dpp(f.y) * inv;
      const float m2 = wave_sum_dpp(f.z) * inv;
      if (lane == 0) {  // per-pillar aux for k4 (fire-and-forget stores)
        *reinterpret_cast<float4*>(aux + (size_t)p * 8) =
            make_float4(m0, m1, m2, ox);
        *reinterpret_cast<float4*>(aux + (size_t)p * 8 + 4) =
            make_float4(oy, __int_as_float(np), 0.f, 0.f);
      }
      const bool valid = lane < np;
      float ft[9] = {f.x,      f.y,      f.z,      f.w,      f.x - m0,
                     f.y - m1, f.z - m2, f.x - ox, f.y - oy};
#pragma unroll
      for (int c = 0; c < 9; ++c) ft[c] = valid ? ft[c] : 0.f;
      int idx = 0;
      float t1 = 0.f, t2 = 0.f;
#pragma unroll
      for (int c = 0; c < 9; ++c) {
        float u = 0.f;
#pragma unroll
        for (int c2 = c; c2 < 9; ++c2) u = fmaf(g[idx++], ft[c2], u);
        t2 = fmaf(ft[c], u, t2);
        t1 = fmaf(ft[c], wsv[c], t1);
      }
      s1 += t1;
      s2 += t2;
      if (!has2) break;
      p = p2;
      f = f2;
      np = np2;
      cx = cx2;
      cy = cy2;
    }
  }
  red[wv][lane] = make_float2(s1, s2);
  __syncthreads();
  if (t < 64) {
    const float v = red[0][t].x + red[1][t].x + red[2][t].x + red[3][t].x;
    partials[((size_t)t * 2 + 0) * S1 + blockIdx.x] = v;
  } else if (t < 128) {
    const int n = t - 64;
    const float v = red[0][n].y + red[1][n].y + red[2][n].y + red[3][n].y;
    partials[((size_t)n * 2 + 1) * S1 + blockIdx.x] = v;
  }
}

// k2: reduce partials (coalesced), compute a[n], b[n]. One block per n.
__global__ __launch_bounds__(256) void k2_stats(
    const float* __restrict__ partials, const float* __restrict__ gamma,
    const float* __restrict__ beta, float* __restrict__ ab, int P) {
  const int n = blockIdx.x, t = threadIdx.x;
  __shared__ float r1[4], r2[4];
  const float* p1 = partials + ((size_t)n * 2 + 0) * S1;
  const float* p2 = partials + ((size_t)n * 2 + 1) * S1;
  float a1 = 0.f, a2 = 0.f;
  for (int b = t; b < S1; b += 256) {
    a1 += p1[b];
    a2 += p2[b];
  }
  a1 = wave_sum(a1);
  a2 = wave_sum(a2);
  const int wv = t >> 6;
  if ((t & 63) == 0) {
    r1[wv] = a1;
    r2[wv] = a2;
  }
  __syncthreads();
  if (t == 0) {
    const float v2 = r1[0] + r1[1] + r1[2] + r1[3];  // sum x
    const float v1 = r2[0] + r2[1] + r2[2] + r2[3];  // sum x^2
    const float invPN = 1.f / ((float)P * 64.f);
    const float mu = v2 * invPN;
    const float var = v1 * invPN - mu * mu;
    const float a = gamma[n] * rsqrtf(var + EPS_);
    const float b = beta[n] - mu * a;
    ab[n] = a;
    ab[64 + n] = b;
  }
}

// k4 (R17, unchanged — best known): BN affine folded INTO the MFMA via
// bias channel. Lane packs its OWN row n=lane: A[n][k] = a_n*ft[k] (k<9,
// masked), A[n][9] = b_n; B[9][o] = 1.0 -> acc4[r] == y directly. Pure
// fmax epilogue; no shab LDS; no block barrier (A_lds per-wave-owned).
__global__ __launch_bounds__(256) void k4_mfma(
    const float* __restrict__ feats, const float* __restrict__ aux,
    const uint32_t* __restrict__ Bpack, const float* __restrict__ ab,
    float* __restrict__ out, int P) {
  __shared__ uint32_t A_lds[4][64][20];  // rows padded to 80 B
  const int t = threadIdx.x, lane = t & 63, wv = t >> 6;
  const int g16 = lane >> 4, l16 = lane & 15;

  uint4 bq[4];
#pragma unroll
  for (int nt = 0; nt < 4; ++nt)
    bq[nt] =
        *reinterpret_cast<const uint4*>(Bpack + ((size_t)nt * 64 + lane) * 4);
  const float a_l = ab[lane];       // BN scale for this lane's row n==lane
  const float b_l = ab[64 + lane];  // BN bias

  // zero the permanently-zero k-slots 5..15 of this wave's rows
  A_lds[wv][lane][5] = 0u;
  A_lds[wv][lane][6] = 0u;
  A_lds[wv][lane][7] = 0u;
  *reinterpret_cast<uint4*>(&A_lds[wv][lane][8]) = make_uint4(0u, 0u, 0u, 0u);
  *reinterpret_cast<uint4*>(&A_lds[wv][lane][12]) = make_uint4(0u, 0u, 0u, 0u);
  // no __syncthreads: each wave exclusively owns A_lds[wv]

  const int p = blockIdx.x * 4 + wv;
  if (p >= P) return;
  const float4 f =
      *reinterpret_cast<const float4*>(feats + (size_t)p * 256 + lane * 4);
  const float4 a0 = *reinterpret_cast<const float4*>(aux + (size_t)p * 8);
  const float4 a1 = *reinterpret_cast<const float4*>(aux + (size_t)p * 8 + 4);

  const float m0 = a0.x, m1 = a0.y, m2 = a0.z, ox = a0.w, oy = a1.x;
  const int np = __float_as_int(a1.y);
  const bool valid = lane < np;
  const float v0 = valid ? a_l * f.x : 0.f;
  const float v1 = valid ? a_l * f.y : 0.f;
  const float v2 = valid ? a_l * f.z : 0.f;
  const float v3 = valid ? a_l * f.w : 0.f;
  const float v4 = valid ? a_l * (f.x - m0) : 0.f;
  const float v5 = valid ? a_l * (f.y - m1) : 0.f;
  const float v6 = valid ? a_l * (f.z - m2) : 0.f;
  const float v7 = valid ? a_l * (f.x - ox) : 0.f;
  const float v8 = valid ? a_l * (f.y - oy) : 0.f;
  union {
    uint32_t u[6];
    uint4 q;
  } pk;
  pk.u[0] = cvtpk(v0, v1);
  pk.u[1] = cvtpk(v2, v3);
  pk.u[2] = cvtpk(v4, v5);
  pk.u[3] = cvtpk(v6, v7);
  pk.u[4] = cvtpk(v8, b_l);  // slot 9 = bias channel (always, even masked)
  // stage this lane's A row (lane == n); same-wave ds_write->ds_read is
  // in-order and each wave owns its A_lds[wv] region: no barrier needed.
  *reinterpret_cast<uint4*>(&A_lds[wv][lane][0]) = pk.q;
  A_lds[wv][lane][4] = pk.u[4];

  bf16x8 afr[4];
#pragma unroll
  for (int mt = 0; mt < 4; ++mt) {
    afr[mt] =
        *reinterpret_cast<const bf16x8*>(&A_lds[wv][mt * 16 + l16][g16 * 4]);
  }
  const f32x4 accz = {0.f, 0.f, 0.f, 0.f};
  float mx[4] = {0.f, 0.f, 0.f, 0.f};  // init 0 == fused relu
#pragma unroll
  for (int mt = 0; mt < 4; ++mt) {
    const bf16x8 a = afr[mt];
#pragma unroll
    for (int nt = 0; nt < 4; ++nt) {
      f32x4 acc4 = __builtin_amdgcn_mfma_f32_16x16x32_bf16(
          a, __builtin_bit_cast(bf16x8, bq[nt]), accz, 0, 0, 0);
#pragma unroll
      for (int r = 0; r < 4; ++r) mx[nt] = fmaxf(mx[nt], acc4[r]);
    }
  }
#pragma unroll
  for (int nt = 0; nt < 4; ++nt) {
    mx[nt] = fmaxf(mx[nt], __shfl_xor(mx[nt], 16));
    mx[nt] = fmaxf(mx[nt], __shfl_xor(mx[nt], 32));
  }
  const float outv =
      (g16 == 0) ? mx[0] : (g16 == 1) ? mx[1] : (g16 == 2) ? mx[2] : mx[3];
  out[(size_t)p * 64 + lane] = outv;  // o = g16*16 + l16 == lane
}

extern "C" void kernel_launch(void* const* d_in, const int* in_sizes, int n_in,
                              void* d_out, int out_size, void* d_ws,
                              size_t ws_size, hipStream_t stream) {
  const float* feats = (const float*)d_in[0];
  const int* npts = (const int*)d_in[1];
  const int* coors = (const int*)d_in[2];
  const float* W = (const float*)d_in[3];
  const float* gamma = (const float*)d_in[4];
  const float* beta = (const float*)d_in[5];
  float* out = (float*)d_out;
  float* ws = (float*)d_ws;

  const int P = in_sizes[1];  // num_points has P elements

  float* ab = ws;                              // [128]: a[64], b[64]
  uint32_t* Bpack = (uint32_t*)(ws + 128);     // [1024] u32 = 4x64 frags
  float* partials = ws + 128 + 1024;           // [64][2][S1]
  float* aux = partials + 64 * 2 * S1;         // [8*P]

  k1_moments<<<S1, 256, 0, stream>>>(feats, npts, coors, W, partials, aux,
                                     Bpack, P);
  k2_stats<<<64, 256, 0, stream>>>(partials, gamma, beta, ab, P);
  const int g1 = (P + 3) / 4;  // 4 waves/block, 1 pillar/wave
  k4_mfma<<<g1, 256, 0, stream>>>(feats, aux, Bpack, ab, out, P);
}